// Round 12
// baseline (304.042 us; speedup 1.0000x reference)
//
#include <hip/hip_runtime.h>
#include <math.h>

#define B_ 4
#define CIN_ 32
#define HID_ 32
#define T_ 31
#define H_ 96
#define W_ 96
#define SP_ (H_*W_)
#define TSP (T_ * SP_)

typedef _Float16 half8 __attribute__((ext_vector_type(8)));
typedef float f32x4 __attribute__((ext_vector_type(4)));
typedef float f32x16 __attribute__((ext_vector_type(16)));

static __device__ inline unsigned int packhh(float a, float b) {
  unsigned short ua = __builtin_bit_cast(unsigned short, (_Float16)a);
  unsigned short ub = __builtin_bit_cast(unsigned short, (_Float16)b);
  return (unsigned int)ua | ((unsigned int)ub << 16);
}

// ---------------------------------------------------------------------------
// Kernel 0: weights fp32 -> fp16 gate-interleaved MFMA A-fragments.
// wr[((ocg*27 + tap)*64 + lane)*8 + i]
//   m = lane&15: gate = m&1, ch = ocg*8 + (m>>1); oc = gate*32 + ch
//   cin = (lane>>4)*8 + i
// ---------------------------------------------------------------------------
__global__ __launch_bounds__(256) void prep_w_kernel(
    const float* __restrict__ w, _Float16* __restrict__ wr) {
  int idx = blockIdx.x * 256 + threadIdx.x;
  if (idx >= 55296) return;
  int i = idx & 7;
  int lane = (idx >> 3) & 63;
  int rest = idx >> 9;             // ocg*27 + tap
  int tap = rest % 27;
  int ocg = rest / 27;
  int m = lane & 15;
  int cin = (lane >> 4) * 8 + i;
  int oc = (m & 1) * 32 + ocg * 8 + (m >> 1);
  wr[idx] = (_Float16)(w[(oc * CIN_ + cin) * 27 + tap]);
}

// ---------------------------------------------------------------------------
// Kernel 1: fused Conv3d (fp16 MFMA) + gating + SERIAL time recurrence.
// R10 dataflow, re-partitioned: block = 2 waves x 32 oc-slots (was 4 x 16).
// Each wave holds BOTH A-frag sets (ocg 2w, 2w+1): 54 half8 = 216 weight
// VGPRs, launch_bounds(128,1) -> 1 wave/SIMD, ~512 VGPR budget, no spill.
// Each brow ds_read_b128 now feeds 2 MFMAs -> per-CU LDS reads HALVED
// (the measured binding resource at R11). 2 blocks/CU interleave for latency.
// No LDS swizzle (R11's swizzle measured harmful; unswizzled 8-lane groups
// are conflict-free by bank arithmetic).
// Grid (96,4): tile 16x6. Ring: 4 slots x [8 rows x 18 cols][pitch 40 f16]
// = 46 KB. h stored packed fp16x2 (channel pair in-lane) as in R10.
// ---------------------------------------------------------------------------
#define PITCH 40
#define SROWS 8
#define SCOLS 18
#define RST (SCOLS * PITCH)                // row stride (halfs)
#define SLICE_HF (SROWS * RST)             // 5760 f16 = 11520 B

__global__ __launch_bounds__(128, 1) void conv_rec_mfma(
    const float* __restrict__ in, const _Float16* __restrict__ wr,
    const float* __restrict__ bias, unsigned int* __restrict__ gout) {
  __shared__ _Float16 in_s[4 * SLICE_HF];   // 46080 B

  const int tid = threadIdx.x;
  const int tile = blockIdx.x;   // 0..95
  const int b = blockIdx.y;      // 0..3
  const int x0 = (tile % 6) * 16;
  const int y0 = (tile / 6) * 6;
  const int lane = tid & 63;
  const int wv = tid >> 6;       // 0..1
  const int px = lane & 15;
  const int kq = lane >> 4;      // 0..3

  // --- per-wave weights: ocg 2w (frag A) and 2w+1 (frag B), 27 taps each ---
  half8 wA[27], wB[27];
  {
    const _Float16* pa = wr + (size_t)(2 * wv) * 27 * 512 + lane * 8;
    const _Float16* pb = wr + (size_t)(2 * wv + 1) * 27 * 512 + lane * 8;
#pragma unroll
    for (int tap = 0; tap < 27; ++tap) {
      wA[tap] = *(const half8*)(pa + tap * 512);
      wB[tap] = *(const half8*)(pb + tap * 512);
    }
  }

  // channels: frag A -> cA = 16w + 2kq (and +1); frag B -> cB = cA + 8
  const int cA = 16 * wv + 2 * kq;
  const int cB = cA + 8;
  f32x4 biasA, biasB;
  biasA[0] = bias[cA];      biasA[1] = bias[32 + cA];
  biasA[2] = bias[cA + 1];  biasA[3] = bias[32 + cA + 1];
  biasB[0] = bias[cB];      biasB[1] = bias[32 + cB];
  biasB[2] = bias[cB + 1];  biasB[3] = bias[32 + cB + 1];

  // ---- staging roles (128 thr): interior 32 jobs, edges 4 per thread ----
  const int s_xi = tid & 15;
  const int s_q  = tid >> 4;       // 0..7 ; job k: rj = k*8+s_q, yy=rj>>5, cin=rj&31
  const int e_cin = tid & 31;
  const int e_y4  = tid >> 5;      // 0..3 -> rows e_y4 and e_y4+4
  const bool has_l = (x0 > 0), has_r = (x0 + 16 < W_);

  const float* inb = in + (size_t)(b * CIN_) * TSP;

  auto stage_full = [&](int ts) {   // prologue only
    _Float16* dst = in_s + (ts & 3) * SLICE_HF;
    const int tso = ts * SP_;
#pragma unroll
    for (int k = 0; k < 32; ++k) {
      int rj = k * 8 + s_q;
      int cin = rj & 31;
      int yy = rj >> 5;
      int gy = y0 - 1 + yy;
      float v = 0.f;
      if ((unsigned)gy < (unsigned)H_)
        v = inb[(size_t)cin * TSP + tso + gy * W_ + x0 + s_xi];
      dst[(yy * SCOLS + s_xi + 1) * PITCH + cin] = (_Float16)v;
    }
#pragma unroll
    for (int j = 0; j < 2; ++j) {
      int yy = e_y4 + 4 * j;
      int gy = y0 - 1 + yy;
      float vl = 0.f, vr = 0.f;
      if ((unsigned)gy < (unsigned)H_) {
        const float* rb = inb + (size_t)e_cin * TSP + tso + gy * W_;
        if (has_l) vl = rb[x0 - 1];
        if (has_r) vr = rb[x0 + 16];
      }
      dst[(yy * SCOLS + 0) * PITCH + e_cin] = (_Float16)vl;
      dst[(yy * SCOLS + 17) * PITCH + e_cin] = (_Float16)vr;
    }
  };

  // prologue: slot 3 = slice -1 = zeros (single pass); slices 0,1 staged
  {
    uint32_t* dz = (uint32_t*)(in_s + 3 * SLICE_HF);
    for (int e = tid; e < SLICE_HF / 2; e += 128) dz[e] = 0u;
  }
  stage_full(0);
  stage_full(1);
  __syncthreads();

  float h[2][6][2];
#pragma unroll
  for (int f = 0; f < 2; ++f)
#pragma unroll
    for (int r = 0; r < 6; ++r) { h[f][r][0] = 0.f; h[f][r][1] = 0.f; }

  // packed-pair planes: prA = 8w + kq, prB = prA + 4
  size_t obA = ((size_t)(b * 32 + 8 * wv + kq) * T_) * SP_ + y0 * W_ + x0 + px;
  size_t obB = obA + (size_t)4 * TSP;

  // brow column offsets (no swizzle)
  int cs[3];
#pragma unroll
  for (int kw = 0; kw < 3; ++kw) cs[kw] = (px + kw) * PITCH + kq * 8;

  for (int t = 0; t < T_; ++t) {
    const int ts = t + 2;

    // ---- phase A: issue stage loads for slice ts (held in regs) ----
    float sv[32], el[2] = {0.f, 0.f}, er[2] = {0.f, 0.f};
    if (ts < T_) {
      const int tso = ts * SP_;
#pragma unroll
      for (int k = 0; k < 32; ++k) {
        int rj = k * 8 + s_q;
        int cin = rj & 31;
        int yy = rj >> 5;
        int gy = y0 - 1 + yy;
        sv[k] = 0.f;
        if ((unsigned)gy < (unsigned)H_)
          sv[k] = inb[(size_t)cin * TSP + tso + gy * W_ + x0 + s_xi];
      }
#pragma unroll
      for (int j = 0; j < 2; ++j) {
        int gy = y0 - 1 + e_y4 + 4 * j;
        if ((unsigned)gy < (unsigned)H_) {
          const float* rb = inb + (size_t)e_cin * TSP + tso + gy * W_;
          if (has_l) el[j] = rb[x0 - 1];
          if (has_r) er[j] = rb[x0 + 16];
        }
      }
    }

    // ---- compute: 27 taps x 6 rows x 2 frags (brow shared) ----
    f32x4 accA[6], accB[6];
#pragma unroll
    for (int r = 0; r < 6; ++r) { accA[r] = biasA; accB[r] = biasB; }

#pragma unroll
    for (int kd = 0; kd < 3; ++kd) {
      const _Float16* sb2 = in_s + ((t + 3 + kd) & 3) * SLICE_HF;  // slice t-1+kd
#pragma unroll
      for (int kw = 0; kw < 3; ++kw) {
        half8 brow[8];
#pragma unroll
        for (int rr = 0; rr < 8; ++rr)
          brow[rr] = *(const half8*)(sb2 + rr * RST + cs[kw]);
#pragma unroll
        for (int kh = 0; kh < 3; ++kh) {
          const int tap = kd * 9 + kh * 3 + kw;
#pragma unroll
          for (int r = 0; r < 6; ++r) {
            accA[r] = __builtin_amdgcn_mfma_f32_16x16x32_f16(wA[tap], brow[r + kh], accA[r], 0, 0, 0);
            accB[r] = __builtin_amdgcn_mfma_f32_16x16x32_f16(wB[tap], brow[r + kh], accB[r], 0, 0, 0);
          }
        }
      }
    }

    // ---- phase B: write staged slice to ring slot (t+2)&3 ----
    if (ts < T_) {
      _Float16* dst = in_s + (ts & 3) * SLICE_HF;
#pragma unroll
      for (int k = 0; k < 32; ++k) {
        int rj = k * 8 + s_q;
        int cin = rj & 31;
        int yy = rj >> 5;
        dst[(yy * SCOLS + s_xi + 1) * PITCH + cin] = (_Float16)sv[k];
      }
#pragma unroll
      for (int j = 0; j < 2; ++j) {
        int yy = e_y4 + 4 * j;
        dst[(yy * SCOLS + 0) * PITCH + e_cin] = (_Float16)el[j];
        dst[(yy * SCOLS + 17) * PITCH + e_cin] = (_Float16)er[j];
      }
    } else if (ts == T_) {
      uint32_t* dz = (uint32_t*)(in_s + (ts & 3) * SLICE_HF);
      for (int e = tid; e < SLICE_HF / 2; e += 128) dz[e] = 0u;
    }

    // ---- gating + recurrence (packed into regs) ----
    unsigned int pkA[6], pkB[6];
#pragma unroll
    for (int r = 0; r < 6; ++r) {
      float z0 = 1.f - 2.f / (1.f + __expf(2.f * accA[r][0]));
      float f0 = 1.f / (1.f + __expf(-accA[r][1]));
      h[0][r][0] = f0 * h[0][r][0] + (1.f - f0) * z0;
      float z1 = 1.f - 2.f / (1.f + __expf(2.f * accA[r][2]));
      float f1 = 1.f / (1.f + __expf(-accA[r][3]));
      h[0][r][1] = f1 * h[0][r][1] + (1.f - f1) * z1;
      pkA[r] = packhh(h[0][r][0], h[0][r][1]);
      float z2 = 1.f - 2.f / (1.f + __expf(2.f * accB[r][0]));
      float f2 = 1.f / (1.f + __expf(-accB[r][1]));
      h[1][r][0] = f2 * h[1][r][0] + (1.f - f2) * z2;
      float z3 = 1.f - 2.f / (1.f + __expf(2.f * accB[r][2]));
      float f3 = 1.f / (1.f + __expf(-accB[r][3]));
      h[1][r][1] = f3 * h[1][r][1] + (1.f - f3) * z3;
      pkB[r] = packhh(h[1][r][0], h[1][r][1]);
    }
    __syncthreads();   // stage writes visible; ring slot safety

    // ---- h-stores AFTER the barrier (drain covered by next barrier) ----
#pragma unroll
    for (int r = 0; r < 6; ++r) {
      gout[obA + r * W_] = pkA[r];
      gout[obB + r * W_] = pkB[r];
    }
    obA += SP_;
    obB += SP_;
  }
}

// ---------------------------------------------------------------------------
// Kernel 2: per-pixel channel attention via 32x32x16 MFMA. (R10/R11, proven)
// Reads packed f16x2 h from u32-planes b*32+pr at own (y,x) tile; writes
// final f32 to planes b*32+c at the same tile -> no cross-block aliasing.
// ---------------------------------------------------------------------------
#define APIT 40
#define PSTR 1288

__global__ __launch_bounds__(512) void attn_mfma(
    unsigned int* __restrict__ g, const float* __restrict__ gamma) {
  __shared__ _Float16 qh_s[16 * PSTR];      // 41216 B
  __shared__ _Float16 qt_s[16 * PSTR];      // 41216 B
  __shared__ _Float16 at_s[8 * 32 * APIT];  // 20480 B

  const int tid = threadIdx.x;
  const int x0 = blockIdx.x * 16;
  const int y = blockIdx.y;
  const int b = blockIdx.z;
  const int lane = tid & 63;
  const int wv = tid >> 6;       // 0..7
  const float gm = gamma[0];

  for (int e = tid; e < 16 * 16 * 31; e += 512) {
    int xi = e & 15;
    int q = e >> 4;
    int t = q % 31;
    int pr = q / 31;
    unsigned int gw = g[((size_t)(b * 32 + pr) * T_ + t) * SP_ + y * W_ + x0 + xi];
    _Float16 h0 = __builtin_bit_cast(_Float16, (unsigned short)(gw & 0xffff));
    _Float16 h1 = __builtin_bit_cast(_Float16, (unsigned short)(gw >> 16));
    int c0 = 2 * pr;
    qh_s[xi * PSTR + c0 * APIT + t] = h0;
    qh_s[xi * PSTR + (c0 + 1) * APIT + t] = h1;
    qt_s[xi * PSTR + t * APIT + c0] = h0;
    qt_s[xi * PSTR + t * APIT + c0 + 1] = h1;
  }
  qh_s[(tid & 15) * PSTR + (tid >> 4) * APIT + 31] = (_Float16)0.f;
  __syncthreads();

  const int cd = lane & 31;
  const int hi = lane >> 5;

#pragma unroll
  for (int pp = 0; pp < 2; ++pp) {
    const int px = wv * 2 + pp;
    const _Float16* qs = qh_s + px * PSTR;
    const _Float16* qt = qt_s + px * PSTR;
    _Float16* as = at_s + wv * (32 * APIT);

    half8 q0 = *(const half8*)(qs + cd * APIT + hi * 8);
    half8 q1 = *(const half8*)(qs + cd * APIT + hi * 8 + 16);
    f32x16 S = {};
    S = __builtin_amdgcn_mfma_f32_32x32x16_f16(q0, q0, S, 0, 0, 0);
    S = __builtin_amdgcn_mfma_f32_32x32x16_f16(q1, q1, S, 0, 0, 0);

    float mx = S[0];
#pragma unroll
    for (int r = 1; r < 16; ++r) mx = fmaxf(mx, S[r]);
    mx = fmaxf(mx, __shfl_xor(mx, 32));
    float sm = 0.f;
    float ev[16];
#pragma unroll
    for (int r = 0; r < 16; ++r) { ev[r] = __expf(S[r] - mx); sm += ev[r]; }
    sm += __shfl_xor(sm, 32);
    const float sc = 0.17677669529663688f / sm;

#pragma unroll
    for (int r = 0; r < 16; ++r) {
      int c = (r & 3) + 8 * (r >> 2) + 4 * hi;
      as[c * APIT + cd] = (_Float16)(ev[r] * sc);
    }

    half8 a0 = *(const half8*)(as + cd * APIT + hi * 8);
    half8 a1 = *(const half8*)(as + cd * APIT + hi * 8 + 16);
    half8 b0 = *(const half8*)(qt + cd * APIT + hi * 8);
    half8 b1 = *(const half8*)(qt + cd * APIT + hi * 8 + 16);
    f32x16 P = {};
    P = __builtin_amdgcn_mfma_f32_32x32x16_f16(a0, b0, P, 0, 0, 0);
    P = __builtin_amdgcn_mfma_f32_32x32x16_f16(a1, b1, P, 0, 0, 0);

#pragma unroll
    for (int r = 0; r < 16; ++r) {
      int c = (r & 3) + 8 * (r >> 2) + 4 * hi;
      qt_s[px * PSTR + cd * APIT + c] = (_Float16)P[r];
    }
  }
  __syncthreads();

  float* gf = (float*)g;
  for (int e = tid; e < 4 * 992; e += 512) {
    int xi4 = e & 3;
    int q = e >> 2;
    int t = q % 31;
    int c = q / 31;
    float4 rv;
#pragma unroll
    for (int j = 0; j < 4; ++j) {
      int xi = xi4 * 4 + j;
      float ah = (float)qt_s[xi * PSTR + t * APIT + c];
      float hv = (float)qh_s[xi * PSTR + c * APIT + t];
      (&rv.x)[j] = gm * ah + hv;
    }
    *(float4*)&gf[((size_t)(b * HID_ + c) * T_ + t) * SP_ + y * W_ + x0 +
                  xi4 * 4] = rv;
  }
}

// ---------------------------------------------------------------------------
extern "C" void kernel_launch(void* const* d_in, const int* in_sizes, int n_in,
                              void* d_out, int out_size, void* d_ws,
                              size_t ws_size, hipStream_t stream) {
  const float* in    = (const float*)d_in[0];  // [4,32,31,96,96]
  const float* w     = (const float*)d_in[1];  // [64,32,3,3,3]
  const float* bias  = (const float*)d_in[2];  // [64]
  const float* gamma = (const float*)d_in[3];  // [1]
  _Float16* wr = (_Float16*)d_ws;              // 110 KB fp16 fragments

  prep_w_kernel<<<216, 256, 0, stream>>>(w, wr);
  conv_rec_mfma<<<dim3(96, 4), 128, 0, stream>>>(
      in, wr, bias, (unsigned int*)d_out);
  attn_mfma<<<dim3(6, 96, 4), 512, 0, stream>>>(
      (unsigned int*)d_out, gamma);
}